// Round 4
// baseline (2226.076 us; speedup 1.0000x reference)
//
#include <hip/hip_runtime.h>

// ChildSumTreeGRU: BRANCH=4, DEPTH=8, N=87381, X=H=512.
// depth-d nodes contiguous at S[d]=(4^d-1)/3; children of p = 4p+1..4p+4.
// R3: pre-split ALL GEMM A-operands to (hi,lo) bf16 at definition site.
// R4: global_load_lds direct staging + granule XOR swizzle (0 bank conflicts);
//     combine fused into z_e GEMM epilogue (EPI 4).
// R5: 2-phase pipeline: double-buffered LDS, stage(k+1) before comp(k).
// R6: B-operand loaded DIRECT from global (weights are L2-resident) -> B LDS
//     tiles deleted: LDS 64->32 KB (3 blocks/CU), LDS reads halve (8/wave/step),
//     staging halves (A only, split across all 4 waves). A path unchanged.

#define NNODES 87381
#define NINT   21845
#define NLEAF  65536

typedef __attribute__((ext_vector_type(8))) __bf16 bf16x8;
typedef __attribute__((ext_vector_type(4))) float f32x4;

__device__ __forceinline__ float sigmoidf_(float x) { return 1.0f / (1.0f + __expf(-x)); }
__device__ __forceinline__ float tanhf_(float x) { return 2.0f / (1.0f + __expf(-2.0f * x)) - 1.0f; }

__device__ __forceinline__ unsigned short bf_rne(float f) {
  unsigned int u = __float_as_uint(f);
  unsigned int r = u + 0x7FFFu + ((u >> 16) & 1u);
  return (unsigned short)(r >> 16);
}
__device__ __forceinline__ void split2(float f, unsigned short& h, unsigned short& l) {
  h = bf_rne(f);
  l = bf_rne(f - __uint_as_float((unsigned int)h << 16));
}
__device__ __forceinline__ float bf2f(unsigned short h) {
  return __uint_as_float((unsigned int)h << 16);
}

// ---------------- split fp32 -> (hi, lo) bf16 ----------------
__global__ __launch_bounds__(256) void split_k(const float* __restrict__ s,
                                               unsigned short* __restrict__ hi,
                                               unsigned short* __restrict__ lo, int n4) {
  int i = blockIdx.x * 256 + threadIdx.x;
  if (i >= n4) return;
  float4 v = *(const float4*)(s + (size_t)i * 4);
  ushort4 h, l;
  split2(v.x, h.x, l.x); split2(v.y, h.y, l.y);
  split2(v.z, h.z, l.z); split2(v.w, h.w, l.w);
  *(ushort4*)(hi + (size_t)i * 4) = h;
  *(ushort4*)(lo + (size_t)i * 4) = l;
}

// ---------------- staging: half a 128x32 bf16 tile via global_load_lds ----
// LDS linear [128][32] (64 B/row). Swizzle: physical 16B-granule p at LDS row lr
// holds global granule p ^ ((lr>>1)&3). Involution: reads XOR the same value.
// Wave-uniform LDS base (l0 + c*512), per-lane global source (allowed).
// Each wave stages 4 of the 8 granule-groups (c0 = 0 or 4).
template <bool CLAMP>
__device__ __forceinline__ void stage_half(const unsigned short* __restrict__ g,
                                           int rows_left, unsigned short* l0,
                                           int lane, int c0) {
#pragma unroll
  for (int c = c0; c < c0 + 4; ++c) {
    const int lr = c * 16 + (lane >> 2);
    const int gr = CLAMP ? (lr < rows_left ? lr : rows_left - 1) : lr;
    const int sg = (lane & 3) ^ ((lr >> 1) & 3);
    __builtin_amdgcn_global_load_lds(
        (const __attribute__((address_space(1))) void*)(g + (size_t)gr * 512 + sg * 8),
        (__attribute__((address_space(3))) void*)(l0 + c * 512), 16, 0, 0);
  }
}

// ---------------- MFMA split-bf16 GEMM ----------------
// C[m,n] = epi( sum_k A[m,k]*B[n,k] ), K=512. tile 128x128, BK=32, 4 waves,
// wave = 64x64 = 4x4 tiles of 16x16x32. 3 MFMAs per tile pair (hh, hl, lh).
// A via LDS (double-buffered, swizzled); B fragments DIRECT from global (L2).
// EPI 1: split(sigmoid(wx[g0+m,n]+acc) * (FH+FL)[m,n]) -> Oh/Ol      (rh)
// EPI 2: C = tanh(wx[g0+m,512+n]+acc)                                (h_cand)
// EPI 3: C = acc + bias[n]                                           (wx)
// EPI 4: fused z_e+combine: acc = ze[child=m][n]; each lane's 4 acc rows are
//        one parent's 4 children. bias = children h (out+cbase*512),
//        C = out+pbase*512 (h_cand in / h out), Oh/Ol = next-level child split.
template <int EPI>
__global__ __launch_bounds__(256) void mgemm(const unsigned short* __restrict__ Ah,
                                             const unsigned short* __restrict__ Al,
                                             const unsigned short* __restrict__ Bh,
                                             const unsigned short* __restrict__ Bl,
                                             float* __restrict__ C, int ldc, int M,
                                             const float* __restrict__ wx, int g0,
                                             const float* __restrict__ bias,
                                             const unsigned short* __restrict__ FH,
                                             const unsigned short* __restrict__ FL,
                                             unsigned short* __restrict__ Oh,
                                             unsigned short* __restrict__ Ol) {
  __shared__ unsigned short As_h[2][128][32];
  __shared__ unsigned short As_l[2][128][32];
  const int t = threadIdx.x;
  const int lane = t & 63, wave = t >> 6;
  const int wm = wave & 1, wn = wave >> 1;
  const int m0 = blockIdx.x * 128, n0 = blockIdx.y * 128;

  f32x4 acc[4][4];
#pragma unroll
  for (int i = 0; i < 4; ++i)
#pragma unroll
    for (int j = 0; j < 4; ++j) acc[i][j] = (f32x4){0.f, 0.f, 0.f, 0.f};

  const int fr = lane & 15, fg = lane >> 4;

  // per-lane B fragment offsets (row-major, k-granule fg)
  int boff[4];
#pragma unroll
  for (int nt = 0; nt < 4; ++nt)
    boff[nt] = (n0 + wn * 64 + nt * 16 + fr) * 512 + fg * 8;

  auto stage = [&](int buf, int k0) {
    if (wave == 0)      stage_half<true>(Ah + (size_t)m0 * 512 + k0, M - m0, &As_h[buf][0][0], lane, 0);
    else if (wave == 1) stage_half<true>(Ah + (size_t)m0 * 512 + k0, M - m0, &As_h[buf][0][0], lane, 4);
    else if (wave == 2) stage_half<true>(Al + (size_t)m0 * 512 + k0, M - m0, &As_l[buf][0][0], lane, 0);
    else                stage_half<true>(Al + (size_t)m0 * 512 + k0, M - m0, &As_l[buf][0][0], lane, 4);
  };

  auto comp = [&](int buf, int k0) {
    bf16x8 ah[4], al[4], bh[4], bl[4];
#pragma unroll
    for (int nt = 0; nt < 4; ++nt) {
      bh[nt] = *(const bf16x8*)(Bh + (size_t)(boff[nt] + k0));
      bl[nt] = *(const bf16x8*)(Bl + (size_t)(boff[nt] + k0));
    }
#pragma unroll
    for (int mt = 0; mt < 4; ++mt) {
      const int row = wm * 64 + mt * 16 + fr;
      const int gp = (fg ^ ((row >> 1) & 3)) * 8;
      ah[mt] = *(const bf16x8*)&As_h[buf][row][gp];
      al[mt] = *(const bf16x8*)&As_l[buf][row][gp];
    }
#pragma unroll
    for (int mt = 0; mt < 4; ++mt)
#pragma unroll
      for (int nt = 0; nt < 4; ++nt) {
        acc[mt][nt] = __builtin_amdgcn_mfma_f32_16x16x32_bf16(ah[mt], bh[nt], acc[mt][nt], 0, 0, 0);
        acc[mt][nt] = __builtin_amdgcn_mfma_f32_16x16x32_bf16(ah[mt], bl[nt], acc[mt][nt], 0, 0, 0);
        acc[mt][nt] = __builtin_amdgcn_mfma_f32_16x16x32_bf16(al[mt], bh[nt], acc[mt][nt], 0, 0, 0);
      }
  };

  stage(0, 0);
  __syncthreads();
  for (int kk = 0; kk < 16; kk += 2) {
    stage(1, (kk + 1) * 32);
    comp(0, kk * 32);
    __syncthreads();
    if (kk < 14) stage(0, (kk + 2) * 32);
    comp(1, (kk + 1) * 32);
    __syncthreads();
  }

  // C/D layout: col=lane&15, row=(lane>>4)*4+reg
  const int ecol = lane & 15;
  const int erow = (lane >> 4) * 4;

  if (EPI == 4) {
#pragma unroll
    for (int mt = 0; mt < 4; ++mt) {
#pragma unroll
      for (int nt = 0; nt < 4; ++nt) {
        const int col = n0 + wn * 64 + nt * 16 + ecol;
        const int row0 = m0 + wm * 64 + mt * 16 + erow;  // multiple of 4
        if (row0 >= M) continue;
        const int p = row0 >> 2;  // local parent index
        const float wz = wx[(size_t)(g0 + p) * 1536 + 1024 + col];
        float hpre = 0.f, zs = 0.f;
#pragma unroll
        for (int r = 0; r < 4; ++r) {
          const float zev = acc[mt][nt][r];
          const float hch = bias[(size_t)(row0 + r) * 512 + col];  // child h (fp32)
          hpre = fmaf(zev, hch, hpre);
          zs += sigmoidf_(zev + wz);
        }
        float* po = C + (size_t)p * 512 + col;
        const float hc = *po;  // h_cand from mgemm<2>
        const float res = hpre + (1.f - zs) * hc;
        *po = res;
        unsigned short oh, ol;
        split2(res, oh, ol);
        Oh[(size_t)p * 512 + col] = oh;
        Ol[(size_t)p * 512 + col] = ol;
      }
    }
    return;
  }

#pragma unroll
  for (int mt = 0; mt < 4; ++mt) {
#pragma unroll
    for (int nt = 0; nt < 4; ++nt) {
      const int col = n0 + wn * 64 + nt * 16 + ecol;
#pragma unroll
      for (int r = 0; r < 4; ++r) {
        const int row = m0 + wm * 64 + mt * 16 + erow + r;
        if (row >= M) continue;
        const float v = acc[mt][nt][r];
        if (EPI == 1) {
          const size_t ix = (size_t)row * 512 + col;
          const float hs = bf2f(FH[ix]) + bf2f(FL[ix]);
          const float rg = sigmoidf_(wx[(size_t)(g0 + row) * 1536 + col] + v);
          unsigned short oh, ol;
          split2(rg * hs, oh, ol);
          Oh[ix] = oh;
          Ol[ix] = ol;
        } else if (EPI == 2) {
          C[(size_t)row * ldc + col] = tanhf_(wx[(size_t)(g0 + row) * 1536 + 512 + col] + v);
        } else {
          C[(size_t)row * ldc + col] = v + bias[col];
        }
      }
    }
  }
}

// ---------------- fused leaf kernel: h = (1-sig(x@Wz^T+bz)) * tanh(x@Wh^T+bh) ----------------
// tile 128 rows x 64 cols; h-gate B rows 512+n0+r, z-gate B rows 1024+n0+r,
// both loaded direct from global (L2-resident weights).
// Writes fp32 h to out AND (hi,lo) split to hcH/hcL.
__global__ __launch_bounds__(256) void mleaf(const unsigned short* __restrict__ xh,
                                             const unsigned short* __restrict__ xl,
                                             const unsigned short* __restrict__ Wh,
                                             const unsigned short* __restrict__ Wl,
                                             const float* __restrict__ bw,
                                             float* __restrict__ out,
                                             unsigned short* __restrict__ hcH,
                                             unsigned short* __restrict__ hcL) {
  __shared__ unsigned short As_h[2][128][32];
  __shared__ unsigned short As_l[2][128][32];
  const int t = threadIdx.x;
  const int lane = t & 63, wave = t >> 6;
  const int wm = wave & 1, wn = wave >> 1;
  const int m0 = blockIdx.x * 128, n0 = blockIdx.y * 64;

  f32x4 acch[4][2], accz[4][2];
#pragma unroll
  for (int i = 0; i < 4; ++i)
#pragma unroll
    for (int j = 0; j < 2; ++j) {
      acch[i][j] = (f32x4){0.f, 0.f, 0.f, 0.f};
      accz[i][j] = (f32x4){0.f, 0.f, 0.f, 0.f};
    }

  const int fr = lane & 15, fg = lane >> 4;

  int boffh[2], boffz[2];
#pragma unroll
  for (int nt = 0; nt < 2; ++nt) {
    boffh[nt] = (512 + n0 + wn * 32 + nt * 16 + fr) * 512 + fg * 8;
    boffz[nt] = (1024 + n0 + wn * 32 + nt * 16 + fr) * 512 + fg * 8;
  }

  auto stage = [&](int buf, int k0) {
    if (wave == 0)      stage_half<false>(xh + (size_t)m0 * 512 + k0, 0, &As_h[buf][0][0], lane, 0);
    else if (wave == 1) stage_half<false>(xh + (size_t)m0 * 512 + k0, 0, &As_h[buf][0][0], lane, 4);
    else if (wave == 2) stage_half<false>(xl + (size_t)m0 * 512 + k0, 0, &As_l[buf][0][0], lane, 0);
    else                stage_half<false>(xl + (size_t)m0 * 512 + k0, 0, &As_l[buf][0][0], lane, 4);
  };

  auto comp = [&](int buf, int k0) {
    bf16x8 ah[4], al[4], bhh[2], bhl[2], bzh[2], bzl[2];
#pragma unroll
    for (int nt = 0; nt < 2; ++nt) {
      bhh[nt] = *(const bf16x8*)(Wh + (size_t)(boffh[nt] + k0));
      bhl[nt] = *(const bf16x8*)(Wl + (size_t)(boffh[nt] + k0));
      bzh[nt] = *(const bf16x8*)(Wh + (size_t)(boffz[nt] + k0));
      bzl[nt] = *(const bf16x8*)(Wl + (size_t)(boffz[nt] + k0));
    }
#pragma unroll
    for (int mt = 0; mt < 4; ++mt) {
      const int row = wm * 64 + mt * 16 + fr;
      const int gp = (fg ^ ((row >> 1) & 3)) * 8;
      ah[mt] = *(const bf16x8*)&As_h[buf][row][gp];
      al[mt] = *(const bf16x8*)&As_l[buf][row][gp];
    }
#pragma unroll
    for (int mt = 0; mt < 4; ++mt)
#pragma unroll
      for (int nt = 0; nt < 2; ++nt) {
        acch[mt][nt] = __builtin_amdgcn_mfma_f32_16x16x32_bf16(ah[mt], bhh[nt], acch[mt][nt], 0, 0, 0);
        acch[mt][nt] = __builtin_amdgcn_mfma_f32_16x16x32_bf16(ah[mt], bhl[nt], acch[mt][nt], 0, 0, 0);
        acch[mt][nt] = __builtin_amdgcn_mfma_f32_16x16x32_bf16(al[mt], bhh[nt], acch[mt][nt], 0, 0, 0);
        accz[mt][nt] = __builtin_amdgcn_mfma_f32_16x16x32_bf16(ah[mt], bzh[nt], accz[mt][nt], 0, 0, 0);
        accz[mt][nt] = __builtin_amdgcn_mfma_f32_16x16x32_bf16(ah[mt], bzl[nt], accz[mt][nt], 0, 0, 0);
        accz[mt][nt] = __builtin_amdgcn_mfma_f32_16x16x32_bf16(al[mt], bzh[nt], accz[mt][nt], 0, 0, 0);
      }
  };

  stage(0, 0);
  __syncthreads();
  for (int kk = 0; kk < 16; kk += 2) {
    stage(1, (kk + 1) * 32);
    comp(0, kk * 32);
    __syncthreads();
    if (kk < 14) stage(0, (kk + 2) * 32);
    comp(1, (kk + 1) * 32);
    __syncthreads();
  }

  const int ecol = lane & 15;
  const int erow = (lane >> 4) * 4;
#pragma unroll
  for (int mt = 0; mt < 4; ++mt) {
#pragma unroll
    for (int nt = 0; nt < 2; ++nt) {
      const int col = n0 + wn * 32 + nt * 16 + ecol;
      const float bh_ = bw[512 + col];
      const float bz_ = bw[1024 + col];
#pragma unroll
      for (int r = 0; r < 4; ++r) {
        const int row = m0 + wm * 64 + mt * 16 + erow + r;
        const float vh = acch[mt][nt][r] + bh_;
        const float vz = accz[mt][nt][r] + bz_;
        const float hval = (1.f - sigmoidf_(vz)) * tanhf_(vh);
        out[(size_t)(NINT + row) * 512 + col] = hval;
        unsigned short oh, ol;
        split2(hval, oh, ol);
        const size_t ix = (size_t)row * 512 + col;
        hcH[ix] = oh;
        hcL[ix] = ol;
      }
    }
  }
}

// ---------------- child sum (writes split directly) ----------------
__global__ __launch_bounds__(256) void child_sum_k(const float* __restrict__ out,
                                                   int cbase, int nl,
                                                   unsigned short* __restrict__ hH,
                                                   unsigned short* __restrict__ hL) {
  const int idx = blockIdx.x * 256 + threadIdx.x;
  if (idx >= nl * 128) return;
  const int i = idx >> 7;
  const int jq = (idx & 127) << 2;
  const float* b = out + (size_t)(cbase + 4 * i) * 512 + jq;
  const float4 a = *(const float4*)(b);
  const float4 c = *(const float4*)(b + 512);
  const float4 d = *(const float4*)(b + 1024);
  const float4 e = *(const float4*)(b + 1536);
  float4 s;
  s.x = a.x + c.x + d.x + e.x;
  s.y = a.y + c.y + d.y + e.y;
  s.z = a.z + c.z + d.z + e.z;
  s.w = a.w + c.w + d.w + e.w;
  ushort4 sh, sl;
  split2(s.x, sh.x, sl.x); split2(s.y, sh.y, sl.y);
  split2(s.z, sh.z, sl.z); split2(s.w, sh.w, sl.w);
  *(ushort4*)(hH + (size_t)i * 512 + jq) = sh;
  *(ushort4*)(hL + (size_t)i * 512 + jq) = sl;
}

extern "C" void kernel_launch(void* const* d_in, const int* in_sizes, int n_in,
                              void* d_out, int out_size, void* d_ws, size_t ws_size,
                              hipStream_t stream) {
  const float* x   = (const float*)d_in[0];
  const float* Ww  = (const float*)d_in[1];
  const float* bw  = (const float*)d_in[2];
  const float* Ur  = (const float*)d_in[3];
  const float* Uhc = (const float*)d_in[4];
  const float* Uz  = (const float*)d_in[5];
  float* out = (float*)d_out;

  // workspace (~521 MB):
  //   R0 (179 MB): x split during GEMM phase; rh split aliases after x dies.
  //   wx_int 134.2 | hsum split 33.6 | hc split A 134.2 | hc split B 33.6 | W splits 6.3
  char* p = (char*)d_ws;
  unsigned short* x_hi = (unsigned short*)p;
  unsigned short* x_lo = x_hi + (size_t)NNODES * 512;
  unsigned short* rhH = (unsigned short*)p;  // alias R0 (x dead in level loop)
  unsigned short* rhL = rhH + (size_t)16384 * 512;
  p += (size_t)NNODES * 512 * 4;
  float* wx_int = (float*)p;                 p += (size_t)NINT * 1536 * 4;
  unsigned short* hsH = (unsigned short*)p;  p += (size_t)16384 * 512 * 2;
  unsigned short* hsL = (unsigned short*)p;  p += (size_t)16384 * 512 * 2;
  unsigned short* hcH = (unsigned short*)p;  p += (size_t)65536 * 512 * 2;
  unsigned short* hcL = (unsigned short*)p;  p += (size_t)65536 * 512 * 2;
  unsigned short* hc2H = (unsigned short*)p; p += (size_t)16384 * 512 * 2;
  unsigned short* hc2L = (unsigned short*)p; p += (size_t)16384 * 512 * 2;
  unsigned short* W_hi = (unsigned short*)p;   p += (size_t)1536 * 512 * 2;
  unsigned short* W_lo = (unsigned short*)p;   p += (size_t)1536 * 512 * 2;
  unsigned short* Ur_hi = (unsigned short*)p;  p += (size_t)512 * 512 * 2;
  unsigned short* Ur_lo = (unsigned short*)p;  p += (size_t)512 * 512 * 2;
  unsigned short* Uhc_hi = (unsigned short*)p; p += (size_t)512 * 512 * 2;
  unsigned short* Uhc_lo = (unsigned short*)p; p += (size_t)512 * 512 * 2;
  unsigned short* Uz_hi = (unsigned short*)p;  p += (size_t)512 * 512 * 2;
  unsigned short* Uz_lo = (unsigned short*)p;  p += (size_t)512 * 512 * 2;

  // 1. split weights + x
  split_k<<<(1536 * 512 / 4 + 255) / 256, 256, 0, stream>>>(Ww, W_hi, W_lo, 1536 * 512 / 4);
  split_k<<<(512 * 512 / 4 + 255) / 256, 256, 0, stream>>>(Ur, Ur_hi, Ur_lo, 512 * 512 / 4);
  split_k<<<(512 * 512 / 4 + 255) / 256, 256, 0, stream>>>(Uhc, Uhc_hi, Uhc_lo, 512 * 512 / 4);
  split_k<<<(512 * 512 / 4 + 255) / 256, 256, 0, stream>>>(Uz, Uz_hi, Uz_lo, 512 * 512 / 4);
  split_k<<<((int)((size_t)NNODES * 512 / 4) + 255) / 256, 256, 0, stream>>>(
      x, x_hi, x_lo, (int)((size_t)NNODES * 512 / 4));

  // 2. wx for internal nodes (3 gates + bias)
  mgemm<3><<<dim3((NINT + 127) / 128, 12), 256, 0, stream>>>(
      x_hi, x_lo, W_hi, W_lo, wx_int, 1536, NINT, nullptr, 0, bw,
      nullptr, nullptr, nullptr, nullptr);

  // 3. fused leaf h -> out (fp32) + hc split
  mleaf<<<dim3(NLEAF / 128, 8), 256, 0, stream>>>(
      x_hi + (size_t)NINT * 512, x_lo + (size_t)NINT * 512, W_hi, W_lo, bw, out, hcH, hcL);

  static const int S[10] = {0, 1, 5, 21, 85, 341, 1365, 5461, 21845, 87381};
  unsigned short *rdH = hcH, *rdL = hcL, *wrH = hc2H, *wrL = hc2L;
  for (int l = 1; l <= 8; ++l) {
    const int d = 8 - l;
    const int pbase = S[d];
    const int nl = S[d + 1] - S[d];
    const int cbase = S[d + 1];
    const int el = 4 * nl;

    child_sum_k<<<(nl * 128 + 255) / 256, 256, 0, stream>>>(out, cbase, nl, hsH, hsL);

    dim3 gr((nl + 127) / 128, 4);
    // rh = sigmoid(wrx + hsum@Ur^T) * hsum  -> split (rhH, rhL)
    mgemm<1><<<gr, 256, 0, stream>>>(hsH, hsL, Ur_hi, Ur_lo, nullptr, 512, nl,
                                     wx_int, pbase, nullptr, hsH, hsL, rhH, rhL);
    // h_cand = tanh(whx + rh@Uhc^T) -> out[parent rows]
    mgemm<2><<<gr, 256, 0, stream>>>(rhH, rhL, Uhc_hi, Uhc_lo,
                                     out + (size_t)pbase * 512, 512, nl,
                                     wx_int, pbase, nullptr, nullptr, nullptr,
                                     nullptr, nullptr);
    // fused z_e + combine: reads child split (rd), child h (out+cbase),
    // h_cand (out+pbase); writes h (out+pbase) + next-level child split (wr).
    dim3 gz((el + 127) / 128, 4);
    mgemm<4><<<gz, 256, 0, stream>>>(rdH, rdL, Uz_hi, Uz_lo,
                                     out + (size_t)pbase * 512, 512, el,
                                     wx_int, pbase, out + (size_t)cbase * 512,
                                     nullptr, nullptr, wrH, wrL);
    // ping-pong child-h split buffers (EPI4 writes parents while reading children)
    unsigned short* tH = rdH; rdH = wrH; wrH = tH;
    unsigned short* tL = rdL; rdL = wrL; wrL = tL;
  }
}

// Round 5
// 1459.304 us; speedup vs baseline: 1.5254x; 1.5254x over previous
//
#include <hip/hip_runtime.h>

// ChildSumTreeGRU: BRANCH=4, DEPTH=8, N=87381, X=H=512.
// depth-d nodes contiguous at S[d]=(4^d-1)/3; children of p = 4p+1..4p+4.
// R3: pre-split ALL GEMM A-operands to (hi,lo) bf16 at definition site.
// R4: global_load_lds direct staging + granule XOR swizzle (0 bank conflicts);
//     combine fused into z_e GEMM epilogue (EPI 4).
// R5: 2-phase pipeline: double-buffered LDS, stage(k+1) before comp(k).
// R6 (REVERTED): B direct-from-global stalled on unprefetched L2 latency.
// R7: 512-thread blocks (8 waves), wave-tile 64x32, same 128x128 tile and
//     64 KB LDS -> 16 waves/CU (4/SIMD) instead of 8: double TLP to hide
//     load latency + barrier drain. B back through LDS (R5 path).

#define NNODES 87381
#define NINT   21845
#define NLEAF  65536

typedef __attribute__((ext_vector_type(8))) __bf16 bf16x8;
typedef __attribute__((ext_vector_type(4))) float f32x4;

__device__ __forceinline__ float sigmoidf_(float x) { return 1.0f / (1.0f + __expf(-x)); }
__device__ __forceinline__ float tanhf_(float x) { return 2.0f / (1.0f + __expf(-2.0f * x)) - 1.0f; }

__device__ __forceinline__ unsigned short bf_rne(float f) {
  unsigned int u = __float_as_uint(f);
  unsigned int r = u + 0x7FFFu + ((u >> 16) & 1u);
  return (unsigned short)(r >> 16);
}
__device__ __forceinline__ void split2(float f, unsigned short& h, unsigned short& l) {
  h = bf_rne(f);
  l = bf_rne(f - __uint_as_float((unsigned int)h << 16));
}
__device__ __forceinline__ float bf2f(unsigned short h) {
  return __uint_as_float((unsigned int)h << 16);
}

// ---------------- split fp32 -> (hi, lo) bf16 ----------------
__global__ __launch_bounds__(256) void split_k(const float* __restrict__ s,
                                               unsigned short* __restrict__ hi,
                                               unsigned short* __restrict__ lo, int n4) {
  int i = blockIdx.x * 256 + threadIdx.x;
  if (i >= n4) return;
  float4 v = *(const float4*)(s + (size_t)i * 4);
  ushort4 h, l;
  split2(v.x, h.x, l.x); split2(v.y, h.y, l.y);
  split2(v.z, h.z, l.z); split2(v.w, h.w, l.w);
  *(ushort4*)(hi + (size_t)i * 4) = h;
  *(ushort4*)(lo + (size_t)i * 4) = l;
}

// ---------------- staging: half a 128x32 bf16 tile via global_load_lds ----
// LDS linear [128][32] (64 B/row). Swizzle: physical 16B-granule p at LDS row lr
// holds global granule p ^ ((lr>>1)&3). Involution: reads XOR the same value.
// Wave-uniform LDS base (l0 + c*512), per-lane global source (allowed).
// Each call stages 4 of the 8 granule-groups (c0 = 0 or 4).
template <bool CLAMP>
__device__ __forceinline__ void stage_half(const unsigned short* __restrict__ g,
                                           int rows_left, unsigned short* l0,
                                           int lane, int c0) {
#pragma unroll
  for (int c = c0; c < c0 + 4; ++c) {
    const int lr = c * 16 + (lane >> 2);
    const int gr = CLAMP ? (lr < rows_left ? lr : rows_left - 1) : lr;
    const int sg = (lane & 3) ^ ((lr >> 1) & 3);
    __builtin_amdgcn_global_load_lds(
        (const __attribute__((address_space(1))) void*)(g + (size_t)gr * 512 + sg * 8),
        (__attribute__((address_space(3))) void*)(l0 + c * 512), 16, 0, 0);
  }
}

// ---------------- MFMA split-bf16 GEMM ----------------
// C[m,n] = epi( sum_k A[m,k]*B[n,k] ), K=512. tile 128x128, BK=32, 8 waves,
// wave = 64x32 = 4x2 tiles of 16x16x32. 3 MFMAs per tile pair (hh, hl, lh).
// EPI 1: split(sigmoid(wx[g0+m,n]+acc) * (FH+FL)[m,n]) -> Oh/Ol      (rh)
// EPI 2: C = tanh(wx[g0+m,512+n]+acc)                                (h_cand)
// EPI 3: C = acc + bias[n]                                           (wx)
// EPI 4: fused z_e+combine: acc = ze[child=m][n]; each lane's 4 acc rows are
//        one parent's 4 children. bias = children h (out+cbase*512),
//        C = out+pbase*512 (h_cand in / h out), Oh/Ol = next-level child split.
template <int EPI>
__global__ __launch_bounds__(512, 4) void mgemm(const unsigned short* __restrict__ Ah,
                                                const unsigned short* __restrict__ Al,
                                                const unsigned short* __restrict__ Bh,
                                                const unsigned short* __restrict__ Bl,
                                                float* __restrict__ C, int ldc, int M,
                                                const float* __restrict__ wx, int g0,
                                                const float* __restrict__ bias,
                                                const unsigned short* __restrict__ FH,
                                                const unsigned short* __restrict__ FL,
                                                unsigned short* __restrict__ Oh,
                                                unsigned short* __restrict__ Ol) {
  __shared__ unsigned short As_h[2][128][32];
  __shared__ unsigned short As_l[2][128][32];
  __shared__ unsigned short Bs_h[2][128][32];
  __shared__ unsigned short Bs_l[2][128][32];
  const int t = threadIdx.x;
  const int lane = t & 63, wave = t >> 6;     // 8 waves
  const int wm = wave & 1, wn = wave >> 1;    // wm: 64-row half, wn: 32-col quarter
  const int m0 = blockIdx.x * 128, n0 = blockIdx.y * 128;

  f32x4 acc[4][2];
#pragma unroll
  for (int i = 0; i < 4; ++i)
#pragma unroll
    for (int j = 0; j < 2; ++j) acc[i][j] = (f32x4){0.f, 0.f, 0.f, 0.f};

  const int fr = lane & 15, fg = lane >> 4;

  auto stage = [&](int buf, int k0) {
    const int c0 = (wave & 1) * 4;
    switch (wave >> 1) {
      case 0: stage_half<true >(Ah + (size_t)m0 * 512 + k0, M - m0, &As_h[buf][0][0], lane, c0); break;
      case 1: stage_half<true >(Al + (size_t)m0 * 512 + k0, M - m0, &As_l[buf][0][0], lane, c0); break;
      case 2: stage_half<false>(Bh + (size_t)n0 * 512 + k0, 0, &Bs_h[buf][0][0], lane, c0); break;
      default: stage_half<false>(Bl + (size_t)n0 * 512 + k0, 0, &Bs_l[buf][0][0], lane, c0); break;
    }
  };

  auto comp = [&](int buf) {
    bf16x8 ah[4], al[4], bh[2], bl[2];
#pragma unroll
    for (int mt = 0; mt < 4; ++mt) {
      const int row = wm * 64 + mt * 16 + fr;
      const int gp = (fg ^ ((row >> 1) & 3)) * 8;
      ah[mt] = *(const bf16x8*)&As_h[buf][row][gp];
      al[mt] = *(const bf16x8*)&As_l[buf][row][gp];
    }
#pragma unroll
    for (int nt = 0; nt < 2; ++nt) {
      const int row = wn * 32 + nt * 16 + fr;
      const int gp = (fg ^ ((row >> 1) & 3)) * 8;
      bh[nt] = *(const bf16x8*)&Bs_h[buf][row][gp];
      bl[nt] = *(const bf16x8*)&Bs_l[buf][row][gp];
    }
#pragma unroll
    for (int mt = 0; mt < 4; ++mt)
#pragma unroll
      for (int nt = 0; nt < 2; ++nt) {
        acc[mt][nt] = __builtin_amdgcn_mfma_f32_16x16x32_bf16(ah[mt], bh[nt], acc[mt][nt], 0, 0, 0);
        acc[mt][nt] = __builtin_amdgcn_mfma_f32_16x16x32_bf16(ah[mt], bl[nt], acc[mt][nt], 0, 0, 0);
        acc[mt][nt] = __builtin_amdgcn_mfma_f32_16x16x32_bf16(al[mt], bh[nt], acc[mt][nt], 0, 0, 0);
      }
  };

  stage(0, 0);
  __syncthreads();
  for (int kk = 0; kk < 16; kk += 2) {
    stage(1, (kk + 1) * 32);   // prefetch tile kk+1
    comp(0);                   // compute tile kk
    __syncthreads();
    if (kk < 14) stage(0, (kk + 2) * 32);
    comp(1);
    __syncthreads();
  }

  // C/D layout: col=lane&15, row=(lane>>4)*4+reg
  const int ecol = lane & 15;
  const int erow = (lane >> 4) * 4;

  if (EPI == 4) {
#pragma unroll
    for (int mt = 0; mt < 4; ++mt) {
#pragma unroll
      for (int nt = 0; nt < 2; ++nt) {
        const int col = n0 + wn * 32 + nt * 16 + ecol;
        const int row0 = m0 + wm * 64 + mt * 16 + erow;  // multiple of 4
        if (row0 >= M) continue;
        const int p = row0 >> 2;  // local parent index
        const float wz = wx[(size_t)(g0 + p) * 1536 + 1024 + col];
        float hpre = 0.f, zs = 0.f;
#pragma unroll
        for (int r = 0; r < 4; ++r) {
          const float zev = acc[mt][nt][r];
          const float hch = bias[(size_t)(row0 + r) * 512 + col];  // child h (fp32)
          hpre = fmaf(zev, hch, hpre);
          zs += sigmoidf_(zev + wz);
        }
        float* po = C + (size_t)p * 512 + col;
        const float hc = *po;  // h_cand from mgemm<2>
        const float res = hpre + (1.f - zs) * hc;
        *po = res;
        unsigned short oh, ol;
        split2(res, oh, ol);
        Oh[(size_t)p * 512 + col] = oh;
        Ol[(size_t)p * 512 + col] = ol;
      }
    }
    return;
  }

#pragma unroll
  for (int mt = 0; mt < 4; ++mt) {
#pragma unroll
    for (int nt = 0; nt < 2; ++nt) {
      const int col = n0 + wn * 32 + nt * 16 + ecol;
#pragma unroll
      for (int r = 0; r < 4; ++r) {
        const int row = m0 + wm * 64 + mt * 16 + erow + r;
        if (row >= M) continue;
        const float v = acc[mt][nt][r];
        if (EPI == 1) {
          const size_t ix = (size_t)row * 512 + col;
          const float hs = bf2f(FH[ix]) + bf2f(FL[ix]);
          const float rg = sigmoidf_(wx[(size_t)(g0 + row) * 1536 + col] + v);
          unsigned short oh, ol;
          split2(rg * hs, oh, ol);
          Oh[ix] = oh;
          Ol[ix] = ol;
        } else if (EPI == 2) {
          C[(size_t)row * ldc + col] = tanhf_(wx[(size_t)(g0 + row) * 1536 + 512 + col] + v);
        } else {
          C[(size_t)row * ldc + col] = v + bias[col];
        }
      }
    }
  }
}

// ---------------- fused leaf kernel: h = (1-sig(x@Wz^T+bz)) * tanh(x@Wh^T+bh) ----------------
// tile 128 rows x 64 cols, 8 waves, wave-tile 64x16; B-LDS rows 0..63 = h-gate
// (W rows 512+n0+r), 64..127 = z-gate (W rows 1024+n0+r).
// Writes fp32 h to out AND (hi,lo) split to hcH/hcL.
__global__ __launch_bounds__(512, 4) void mleaf(const unsigned short* __restrict__ xh,
                                                const unsigned short* __restrict__ xl,
                                                const unsigned short* __restrict__ Wh,
                                                const unsigned short* __restrict__ Wl,
                                                const float* __restrict__ bw,
                                                float* __restrict__ out,
                                                unsigned short* __restrict__ hcH,
                                                unsigned short* __restrict__ hcL) {
  __shared__ unsigned short As_h[2][128][32];
  __shared__ unsigned short As_l[2][128][32];
  __shared__ unsigned short Bs_h[2][128][32];
  __shared__ unsigned short Bs_l[2][128][32];
  const int t = threadIdx.x;
  const int lane = t & 63, wave = t >> 6;
  const int wm = wave & 1, wn = wave >> 1;  // wn 0..3: 16-col quarters
  const int m0 = blockIdx.x * 128, n0 = blockIdx.y * 64;

  f32x4 acch[4], accz[4];
#pragma unroll
  for (int i = 0; i < 4; ++i) {
    acch[i] = (f32x4){0.f, 0.f, 0.f, 0.f};
    accz[i] = (f32x4){0.f, 0.f, 0.f, 0.f};
  }

  const int fr = lane & 15, fg = lane >> 4;

  auto stage = [&](int buf, int k0) {
    const int c0 = (wave & 1) * 4;
    const int grp = wave >> 1;
    if (grp == 0) {
      stage_half<false>(xh + (size_t)m0 * 512 + k0, 0, &As_h[buf][0][0], lane, c0);
    } else if (grp == 1) {
      stage_half<false>(xl + (size_t)m0 * 512 + k0, 0, &As_l[buf][0][0], lane, c0);
    } else {
      const unsigned short* Ws = (grp == 2) ? Wh : Wl;
      unsigned short* dst = (grp == 2) ? &Bs_h[buf][0][0] : &Bs_l[buf][0][0];
#pragma unroll
      for (int c = c0; c < c0 + 4; ++c) {
        const int lr = c * 16 + (lane >> 2);
        const int grow = (lr < 64) ? (512 + n0 + lr) : (1024 + n0 + (lr - 64));
        const int sg = (lane & 3) ^ ((lr >> 1) & 3);
        __builtin_amdgcn_global_load_lds(
            (const __attribute__((address_space(1))) void*)(Ws + (size_t)grow * 512 + k0 + sg * 8),
            (__attribute__((address_space(3))) void*)(dst + c * 512), 16, 0, 0);
      }
    }
  };

  auto comp = [&](int buf) {
    bf16x8 ah[4], al[4], bhh, bhl, bzh, bzl;
    {
      const int rh_ = wn * 16 + fr;
      const int rz_ = 64 + rh_;
      const int gph = (fg ^ ((rh_ >> 1) & 3)) * 8;
      const int gpz = (fg ^ ((rz_ >> 1) & 3)) * 8;
      bhh = *(const bf16x8*)&Bs_h[buf][rh_][gph];
      bhl = *(const bf16x8*)&Bs_l[buf][rh_][gph];
      bzh = *(const bf16x8*)&Bs_h[buf][rz_][gpz];
      bzl = *(const bf16x8*)&Bs_l[buf][rz_][gpz];
    }
#pragma unroll
    for (int mt = 0; mt < 4; ++mt) {
      const int row = wm * 64 + mt * 16 + fr;
      const int gp = (fg ^ ((row >> 1) & 3)) * 8;
      ah[mt] = *(const bf16x8*)&As_h[buf][row][gp];
      al[mt] = *(const bf16x8*)&As_l[buf][row][gp];
    }
#pragma unroll
    for (int mt = 0; mt < 4; ++mt) {
      acch[mt] = __builtin_amdgcn_mfma_f32_16x16x32_bf16(ah[mt], bhh, acch[mt], 0, 0, 0);
      acch[mt] = __builtin_amdgcn_mfma_f32_16x16x32_bf16(ah[mt], bhl, acch[mt], 0, 0, 0);
      acch[mt] = __builtin_amdgcn_mfma_f32_16x16x32_bf16(al[mt], bhh, acch[mt], 0, 0, 0);
      accz[mt] = __builtin_amdgcn_mfma_f32_16x16x32_bf16(ah[mt], bzh, accz[mt], 0, 0, 0);
      accz[mt] = __builtin_amdgcn_mfma_f32_16x16x32_bf16(ah[mt], bzl, accz[mt], 0, 0, 0);
      accz[mt] = __builtin_amdgcn_mfma_f32_16x16x32_bf16(al[mt], bzh, accz[mt], 0, 0, 0);
    }
  };

  stage(0, 0);
  __syncthreads();
  for (int kk = 0; kk < 16; kk += 2) {
    stage(1, (kk + 1) * 32);
    comp(0);
    __syncthreads();
    if (kk < 14) stage(0, (kk + 2) * 32);
    comp(1);
    __syncthreads();
  }

  const int ecol = lane & 15;
  const int erow = (lane >> 4) * 4;
  const int col = n0 + wn * 16 + ecol;
  const float bh_ = bw[512 + col];
  const float bz_ = bw[1024 + col];
#pragma unroll
  for (int mt = 0; mt < 4; ++mt) {
#pragma unroll
    for (int r = 0; r < 4; ++r) {
      const int row = m0 + wm * 64 + mt * 16 + erow + r;
      const float vh = acch[mt][r] + bh_;
      const float vz = accz[mt][r] + bz_;
      const float hval = (1.f - sigmoidf_(vz)) * tanhf_(vh);
      out[(size_t)(NINT + row) * 512 + col] = hval;
      unsigned short oh, ol;
      split2(hval, oh, ol);
      const size_t ix = (size_t)row * 512 + col;
      hcH[ix] = oh;
      hcL[ix] = ol;
    }
  }
}

// ---------------- child sum (writes split directly) ----------------
__global__ __launch_bounds__(256) void child_sum_k(const float* __restrict__ out,
                                                   int cbase, int nl,
                                                   unsigned short* __restrict__ hH,
                                                   unsigned short* __restrict__ hL) {
  const int idx = blockIdx.x * 256 + threadIdx.x;
  if (idx >= nl * 128) return;
  const int i = idx >> 7;
  const int jq = (idx & 127) << 2;
  const float* b = out + (size_t)(cbase + 4 * i) * 512 + jq;
  const float4 a = *(const float4*)(b);
  const float4 c = *(const float4*)(b + 512);
  const float4 d = *(const float4*)(b + 1024);
  const float4 e = *(const float4*)(b + 1536);
  float4 s;
  s.x = a.x + c.x + d.x + e.x;
  s.y = a.y + c.y + d.y + e.y;
  s.z = a.z + c.z + d.z + e.z;
  s.w = a.w + c.w + d.w + e.w;
  ushort4 sh, sl;
  split2(s.x, sh.x, sl.x); split2(s.y, sh.y, sl.y);
  split2(s.z, sh.z, sl.z); split2(s.w, sh.w, sl.w);
  *(ushort4*)(hH + (size_t)i * 512 + jq) = sh;
  *(ushort4*)(hL + (size_t)i * 512 + jq) = sl;
}

extern "C" void kernel_launch(void* const* d_in, const int* in_sizes, int n_in,
                              void* d_out, int out_size, void* d_ws, size_t ws_size,
                              hipStream_t stream) {
  const float* x   = (const float*)d_in[0];
  const float* Ww  = (const float*)d_in[1];
  const float* bw  = (const float*)d_in[2];
  const float* Ur  = (const float*)d_in[3];
  const float* Uhc = (const float*)d_in[4];
  const float* Uz  = (const float*)d_in[5];
  float* out = (float*)d_out;

  // workspace (~521 MB):
  //   R0 (179 MB): x split during GEMM phase; rh split aliases after x dies.
  //   wx_int 134.2 | hsum split 33.6 | hc split A 134.2 | hc split B 33.6 | W splits 6.3
  char* p = (char*)d_ws;
  unsigned short* x_hi = (unsigned short*)p;
  unsigned short* x_lo = x_hi + (size_t)NNODES * 512;
  unsigned short* rhH = (unsigned short*)p;  // alias R0 (x dead in level loop)
  unsigned short* rhL = rhH + (size_t)16384 * 512;
  p += (size_t)NNODES * 512 * 4;
  float* wx_int = (float*)p;                 p += (size_t)NINT * 1536 * 4;
  unsigned short* hsH = (unsigned short*)p;  p += (size_t)16384 * 512 * 2;
  unsigned short* hsL = (unsigned short*)p;  p += (size_t)16384 * 512 * 2;
  unsigned short* hcH = (unsigned short*)p;  p += (size_t)65536 * 512 * 2;
  unsigned short* hcL = (unsigned short*)p;  p += (size_t)65536 * 512 * 2;
  unsigned short* hc2H = (unsigned short*)p; p += (size_t)16384 * 512 * 2;
  unsigned short* hc2L = (unsigned short*)p; p += (size_t)16384 * 512 * 2;
  unsigned short* W_hi = (unsigned short*)p;   p += (size_t)1536 * 512 * 2;
  unsigned short* W_lo = (unsigned short*)p;   p += (size_t)1536 * 512 * 2;
  unsigned short* Ur_hi = (unsigned short*)p;  p += (size_t)512 * 512 * 2;
  unsigned short* Ur_lo = (unsigned short*)p;  p += (size_t)512 * 512 * 2;
  unsigned short* Uhc_hi = (unsigned short*)p; p += (size_t)512 * 512 * 2;
  unsigned short* Uhc_lo = (unsigned short*)p; p += (size_t)512 * 512 * 2;
  unsigned short* Uz_hi = (unsigned short*)p;  p += (size_t)512 * 512 * 2;
  unsigned short* Uz_lo = (unsigned short*)p;  p += (size_t)512 * 512 * 2;

  // 1. split weights + x
  split_k<<<(1536 * 512 / 4 + 255) / 256, 256, 0, stream>>>(Ww, W_hi, W_lo, 1536 * 512 / 4);
  split_k<<<(512 * 512 / 4 + 255) / 256, 256, 0, stream>>>(Ur, Ur_hi, Ur_lo, 512 * 512 / 4);
  split_k<<<(512 * 512 / 4 + 255) / 256, 256, 0, stream>>>(Uhc, Uhc_hi, Uhc_lo, 512 * 512 / 4);
  split_k<<<(512 * 512 / 4 + 255) / 256, 256, 0, stream>>>(Uz, Uz_hi, Uz_lo, 512 * 512 / 4);
  split_k<<<((int)((size_t)NNODES * 512 / 4) + 255) / 256, 256, 0, stream>>>(
      x, x_hi, x_lo, (int)((size_t)NNODES * 512 / 4));

  // 2. wx for internal nodes (3 gates + bias)
  mgemm<3><<<dim3((NINT + 127) / 128, 12), 512, 0, stream>>>(
      x_hi, x_lo, W_hi, W_lo, wx_int, 1536, NINT, nullptr, 0, bw,
      nullptr, nullptr, nullptr, nullptr);

  // 3. fused leaf h -> out (fp32) + hc split
  mleaf<<<dim3(NLEAF / 128, 8), 512, 0, stream>>>(
      x_hi + (size_t)NINT * 512, x_lo + (size_t)NINT * 512, W_hi, W_lo, bw, out, hcH, hcL);

  static const int S[10] = {0, 1, 5, 21, 85, 341, 1365, 5461, 21845, 87381};
  unsigned short *rdH = hcH, *rdL = hcL, *wrH = hc2H, *wrL = hc2L;
  for (int l = 1; l <= 8; ++l) {
    const int d = 8 - l;
    const int pbase = S[d];
    const int nl = S[d + 1] - S[d];
    const int cbase = S[d + 1];
    const int el = 4 * nl;

    child_sum_k<<<(nl * 128 + 255) / 256, 256, 0, stream>>>(out, cbase, nl, hsH, hsL);

    dim3 gr((nl + 127) / 128, 4);
    // rh = sigmoid(wrx + hsum@Ur^T) * hsum  -> split (rhH, rhL)
    mgemm<1><<<gr, 512, 0, stream>>>(hsH, hsL, Ur_hi, Ur_lo, nullptr, 512, nl,
                                     wx_int, pbase, nullptr, hsH, hsL, rhH, rhL);
    // h_cand = tanh(whx + rh@Uhc^T) -> out[parent rows]
    mgemm<2><<<gr, 512, 0, stream>>>(rhH, rhL, Uhc_hi, Uhc_lo,
                                     out + (size_t)pbase * 512, 512, nl,
                                     wx_int, pbase, nullptr, nullptr, nullptr,
                                     nullptr, nullptr);
    // fused z_e + combine: reads child split (rd), child h (out+cbase),
    // h_cand (out+pbase); writes h (out+pbase) + next-level child split (wr).
    dim3 gz((el + 127) / 128, 4);
    mgemm<4><<<gz, 512, 0, stream>>>(rdH, rdL, Uz_hi, Uz_lo,
                                     out + (size_t)pbase * 512, 512, el,
                                     wx_int, pbase, out + (size_t)cbase * 512,
                                     nullptr, nullptr, wrH, wrL);
    // ping-pong child-h split buffers (EPI4 writes parents while reading children)
    unsigned short* tH = rdH; rdH = wrH; wrH = tH;
    unsigned short* tL = rdL; rdL = wrL; wrL = tL;
  }
}

// Round 6
// 1420.366 us; speedup vs baseline: 1.5673x; 1.0274x over previous
//
#include <hip/hip_runtime.h>

// ChildSumTreeGRU: BRANCH=4, DEPTH=8, N=87381, X=H=512.
// depth-d nodes contiguous at S[d]=(4^d-1)/3; children of p = 4p+1..4p+4.
// R3: pre-split ALL GEMM A-operands to (hi,lo) bf16 at definition site.
// R4: global_load_lds direct staging + granule XOR swizzle (0 bank conflicts);
//     combine fused into z_e GEMM epilogue (EPI 4).
// R5: 2-phase pipeline: double-buffered LDS, stage(k+1) before comp(k).
// R7: 512-thread blocks (8 waves) -> 16 waves/CU.
// R8: panel-major + XCD-chunked block remap (T1, bijective m204 formula):
//     blocks sharing an A-panel are contiguous AND on the same XCD ->
//     A-panel fetched once into one L2, re-read 8-12x as hits.
//     (R7 grid was n-major: A re-streamed 8-12x from HBM, FETCH 546 MB vs
//      ideal ~140 MB on mleaf.)

#define NNODES 87381
#define NINT   21845
#define NLEAF  65536

typedef __attribute__((ext_vector_type(8))) __bf16 bf16x8;
typedef __attribute__((ext_vector_type(4))) float f32x4;

__device__ __forceinline__ float sigmoidf_(float x) { return 1.0f / (1.0f + __expf(-x)); }
__device__ __forceinline__ float tanhf_(float x) { return 2.0f / (1.0f + __expf(-2.0f * x)) - 1.0f; }

__device__ __forceinline__ unsigned short bf_rne(float f) {
  unsigned int u = __float_as_uint(f);
  unsigned int r = u + 0x7FFFu + ((u >> 16) & 1u);
  return (unsigned short)(r >> 16);
}
__device__ __forceinline__ void split2(float f, unsigned short& h, unsigned short& l) {
  h = bf_rne(f);
  l = bf_rne(f - __uint_as_float((unsigned int)h << 16));
}
__device__ __forceinline__ float bf2f(unsigned short h) {
  return __uint_as_float((unsigned int)h << 16);
}

// XCD-chunked bijective remap (m204): hardware block h (round-robin h%8 over
// XCDs) -> logical block L such that contiguous L live on one XCD.
__device__ __forceinline__ int xcd_remap(int h, int nwg) {
  const int q = nwg >> 3, r = nwg & 7;
  const int xcd = h & 7, slot = h >> 3;
  return (xcd < r ? xcd * (q + 1) : r * (q + 1) + (xcd - r) * q) + slot;
}

// ---------------- split fp32 -> (hi, lo) bf16 ----------------
__global__ __launch_bounds__(256) void split_k(const float* __restrict__ s,
                                               unsigned short* __restrict__ hi,
                                               unsigned short* __restrict__ lo, int n4) {
  int i = blockIdx.x * 256 + threadIdx.x;
  if (i >= n4) return;
  float4 v = *(const float4*)(s + (size_t)i * 4);
  ushort4 h, l;
  split2(v.x, h.x, l.x); split2(v.y, h.y, l.y);
  split2(v.z, h.z, l.z); split2(v.w, h.w, l.w);
  *(ushort4*)(hi + (size_t)i * 4) = h;
  *(ushort4*)(lo + (size_t)i * 4) = l;
}

// ---------------- staging: half a 128x32 bf16 tile via global_load_lds ----
// LDS linear [128][32] (64 B/row). Swizzle: physical 16B-granule p at LDS row lr
// holds global granule p ^ ((lr>>1)&3). Involution: reads XOR the same value.
// Wave-uniform LDS base (l0 + c*512), per-lane global source (allowed).
// Each call stages 4 of the 8 granule-groups (c0 = 0 or 4).
template <bool CLAMP>
__device__ __forceinline__ void stage_half(const unsigned short* __restrict__ g,
                                           int rows_left, unsigned short* l0,
                                           int lane, int c0) {
#pragma unroll
  for (int c = c0; c < c0 + 4; ++c) {
    const int lr = c * 16 + (lane >> 2);
    const int gr = CLAMP ? (lr < rows_left ? lr : rows_left - 1) : lr;
    const int sg = (lane & 3) ^ ((lr >> 1) & 3);
    __builtin_amdgcn_global_load_lds(
        (const __attribute__((address_space(1))) void*)(g + (size_t)gr * 512 + sg * 8),
        (__attribute__((address_space(3))) void*)(l0 + c * 512), 16, 0, 0);
  }
}

// ---------------- MFMA split-bf16 GEMM ----------------
// C[m,n] = epi( sum_k A[m,k]*B[n,k] ), K=512. tile 128x128, BK=32, 8 waves,
// wave = 64x32 = 4x2 tiles of 16x16x32. 3 MFMAs per tile pair (hh, hl, lh).
// Grid: 1-D, logical L = mb*nnb + nb (m-major), XCD-chunked via xcd_remap.
// EPI 1: split(sigmoid(wx[g0+m,n]+acc) * (FH+FL)[m,n]) -> Oh/Ol      (rh)
// EPI 2: C = tanh(wx[g0+m,512+n]+acc)                                (h_cand)
// EPI 3: C = acc + bias[n]                                           (wx)
// EPI 4: fused z_e+combine: acc = ze[child=m][n]; each lane's 4 acc rows are
//        one parent's 4 children. bias = children h (out+cbase*512),
//        C = out+pbase*512 (h_cand in / h out), Oh/Ol = next-level child split.
template <int EPI>
__global__ __launch_bounds__(512, 4) void mgemm(const unsigned short* __restrict__ Ah,
                                                const unsigned short* __restrict__ Al,
                                                const unsigned short* __restrict__ Bh,
                                                const unsigned short* __restrict__ Bl,
                                                float* __restrict__ C, int ldc, int M,
                                                const float* __restrict__ wx, int g0,
                                                const float* __restrict__ bias,
                                                const unsigned short* __restrict__ FH,
                                                const unsigned short* __restrict__ FL,
                                                unsigned short* __restrict__ Oh,
                                                unsigned short* __restrict__ Ol,
                                                int nnb) {
  __shared__ unsigned short As_h[2][128][32];
  __shared__ unsigned short As_l[2][128][32];
  __shared__ unsigned short Bs_h[2][128][32];
  __shared__ unsigned short Bs_l[2][128][32];
  const int t = threadIdx.x;
  const int lane = t & 63, wave = t >> 6;     // 8 waves
  const int wm = wave & 1, wn = wave >> 1;    // wm: 64-row half, wn: 32-col quarter
  const int L = xcd_remap(blockIdx.x, gridDim.x);
  const int m0 = (L / nnb) * 128, n0 = (L % nnb) * 128;

  f32x4 acc[4][2];
#pragma unroll
  for (int i = 0; i < 4; ++i)
#pragma unroll
    for (int j = 0; j < 2; ++j) acc[i][j] = (f32x4){0.f, 0.f, 0.f, 0.f};

  const int fr = lane & 15, fg = lane >> 4;

  auto stage = [&](int buf, int k0) {
    const int c0 = (wave & 1) * 4;
    switch (wave >> 1) {
      case 0: stage_half<true >(Ah + (size_t)m0 * 512 + k0, M - m0, &As_h[buf][0][0], lane, c0); break;
      case 1: stage_half<true >(Al + (size_t)m0 * 512 + k0, M - m0, &As_l[buf][0][0], lane, c0); break;
      case 2: stage_half<false>(Bh + (size_t)n0 * 512 + k0, 0, &Bs_h[buf][0][0], lane, c0); break;
      default: stage_half<false>(Bl + (size_t)n0 * 512 + k0, 0, &Bs_l[buf][0][0], lane, c0); break;
    }
  };

  auto comp = [&](int buf) {
    bf16x8 ah[4], al[4], bh[2], bl[2];
#pragma unroll
    for (int mt = 0; mt < 4; ++mt) {
      const int row = wm * 64 + mt * 16 + fr;
      const int gp = (fg ^ ((row >> 1) & 3)) * 8;
      ah[mt] = *(const bf16x8*)&As_h[buf][row][gp];
      al[mt] = *(const bf16x8*)&As_l[buf][row][gp];
    }
#pragma unroll
    for (int nt = 0; nt < 2; ++nt) {
      const int row = wn * 32 + nt * 16 + fr;
      const int gp = (fg ^ ((row >> 1) & 3)) * 8;
      bh[nt] = *(const bf16x8*)&Bs_h[buf][row][gp];
      bl[nt] = *(const bf16x8*)&Bs_l[buf][row][gp];
    }
#pragma unroll
    for (int mt = 0; mt < 4; ++mt)
#pragma unroll
      for (int nt = 0; nt < 2; ++nt) {
        acc[mt][nt] = __builtin_amdgcn_mfma_f32_16x16x32_bf16(ah[mt], bh[nt], acc[mt][nt], 0, 0, 0);
        acc[mt][nt] = __builtin_amdgcn_mfma_f32_16x16x32_bf16(ah[mt], bl[nt], acc[mt][nt], 0, 0, 0);
        acc[mt][nt] = __builtin_amdgcn_mfma_f32_16x16x32_bf16(al[mt], bh[nt], acc[mt][nt], 0, 0, 0);
      }
  };

  stage(0, 0);
  __syncthreads();
  for (int kk = 0; kk < 16; kk += 2) {
    stage(1, (kk + 1) * 32);   // prefetch tile kk+1
    comp(0);                   // compute tile kk
    __syncthreads();
    if (kk < 14) stage(0, (kk + 2) * 32);
    comp(1);
    __syncthreads();
  }

  // C/D layout: col=lane&15, row=(lane>>4)*4+reg
  const int ecol = lane & 15;
  const int erow = (lane >> 4) * 4;

  if (EPI == 4) {
#pragma unroll
    for (int mt = 0; mt < 4; ++mt) {
#pragma unroll
      for (int nt = 0; nt < 2; ++nt) {
        const int col = n0 + wn * 32 + nt * 16 + ecol;
        const int row0 = m0 + wm * 64 + mt * 16 + erow;  // multiple of 4
        if (row0 >= M) continue;
        const int p = row0 >> 2;  // local parent index
        const float wz = wx[(size_t)(g0 + p) * 1536 + 1024 + col];
        float hpre = 0.f, zs = 0.f;
#pragma unroll
        for (int r = 0; r < 4; ++r) {
          const float zev = acc[mt][nt][r];
          const float hch = bias[(size_t)(row0 + r) * 512 + col];  // child h (fp32)
          hpre = fmaf(zev, hch, hpre);
          zs += sigmoidf_(zev + wz);
        }
        float* po = C + (size_t)p * 512 + col;
        const float hc = *po;  // h_cand from mgemm<2>
        const float res = hpre + (1.f - zs) * hc;
        *po = res;
        unsigned short oh, ol;
        split2(res, oh, ol);
        Oh[(size_t)p * 512 + col] = oh;
        Ol[(size_t)p * 512 + col] = ol;
      }
    }
    return;
  }

#pragma unroll
  for (int mt = 0; mt < 4; ++mt) {
#pragma unroll
    for (int nt = 0; nt < 2; ++nt) {
      const int col = n0 + wn * 32 + nt * 16 + ecol;
#pragma unroll
      for (int r = 0; r < 4; ++r) {
        const int row = m0 + wm * 64 + mt * 16 + erow + r;
        if (row >= M) continue;
        const float v = acc[mt][nt][r];
        if (EPI == 1) {
          const size_t ix = (size_t)row * 512 + col;
          const float hs = bf2f(FH[ix]) + bf2f(FL[ix]);
          const float rg = sigmoidf_(wx[(size_t)(g0 + row) * 1536 + col] + v);
          unsigned short oh, ol;
          split2(rg * hs, oh, ol);
          Oh[ix] = oh;
          Ol[ix] = ol;
        } else if (EPI == 2) {
          C[(size_t)row * ldc + col] = tanhf_(wx[(size_t)(g0 + row) * 1536 + 512 + col] + v);
        } else {
          C[(size_t)row * ldc + col] = v + bias[col];
        }
      }
    }
  }
}

// ---------------- fused leaf kernel: h = (1-sig(x@Wz^T+bz)) * tanh(x@Wh^T+bh) ----------------
// tile 128 rows x 64 cols, 8 waves, wave-tile 64x16; B-LDS rows 0..63 = h-gate
// (W rows 512+n0+r), 64..127 = z-gate (W rows 1024+n0+r).
// Grid: 1-D, logical L = mb*8 + nb (m-major), XCD-chunked.
// Writes fp32 h to out AND (hi,lo) split to hcH/hcL.
__global__ __launch_bounds__(512, 4) void mleaf(const unsigned short* __restrict__ xh,
                                                const unsigned short* __restrict__ xl,
                                                const unsigned short* __restrict__ Wh,
                                                const unsigned short* __restrict__ Wl,
                                                const float* __restrict__ bw,
                                                float* __restrict__ out,
                                                unsigned short* __restrict__ hcH,
                                                unsigned short* __restrict__ hcL) {
  __shared__ unsigned short As_h[2][128][32];
  __shared__ unsigned short As_l[2][128][32];
  __shared__ unsigned short Bs_h[2][128][32];
  __shared__ unsigned short Bs_l[2][128][32];
  const int t = threadIdx.x;
  const int lane = t & 63, wave = t >> 6;
  const int wm = wave & 1, wn = wave >> 1;  // wn 0..3: 16-col quarters
  const int L = xcd_remap(blockIdx.x, gridDim.x);
  const int m0 = (L >> 3) * 128, n0 = (L & 7) * 64;

  f32x4 acch[4], accz[4];
#pragma unroll
  for (int i = 0; i < 4; ++i) {
    acch[i] = (f32x4){0.f, 0.f, 0.f, 0.f};
    accz[i] = (f32x4){0.f, 0.f, 0.f, 0.f};
  }

  const int fr = lane & 15, fg = lane >> 4;

  auto stage = [&](int buf, int k0) {
    const int c0 = (wave & 1) * 4;
    const int grp = wave >> 1;
    if (grp == 0) {
      stage_half<false>(xh + (size_t)m0 * 512 + k0, 0, &As_h[buf][0][0], lane, c0);
    } else if (grp == 1) {
      stage_half<false>(xl + (size_t)m0 * 512 + k0, 0, &As_l[buf][0][0], lane, c0);
    } else {
      const unsigned short* Ws = (grp == 2) ? Wh : Wl;
      unsigned short* dst = (grp == 2) ? &Bs_h[buf][0][0] : &Bs_l[buf][0][0];
#pragma unroll
      for (int c = c0; c < c0 + 4; ++c) {
        const int lr = c * 16 + (lane >> 2);
        const int grow = (lr < 64) ? (512 + n0 + lr) : (1024 + n0 + (lr - 64));
        const int sg = (lane & 3) ^ ((lr >> 1) & 3);
        __builtin_amdgcn_global_load_lds(
            (const __attribute__((address_space(1))) void*)(Ws + (size_t)grow * 512 + k0 + sg * 8),
            (__attribute__((address_space(3))) void*)(dst + c * 512), 16, 0, 0);
      }
    }
  };

  auto comp = [&](int buf) {
    bf16x8 ah[4], al[4], bhh, bhl, bzh, bzl;
    {
      const int rh_ = wn * 16 + fr;
      const int rz_ = 64 + rh_;
      const int gph = (fg ^ ((rh_ >> 1) & 3)) * 8;
      const int gpz = (fg ^ ((rz_ >> 1) & 3)) * 8;
      bhh = *(const bf16x8*)&Bs_h[buf][rh_][gph];
      bhl = *(const bf16x8*)&Bs_l[buf][rh_][gph];
      bzh = *(const bf16x8*)&Bs_h[buf][rz_][gpz];
      bzl = *(const bf16x8*)&Bs_l[buf][rz_][gpz];
    }
#pragma unroll
    for (int mt = 0; mt < 4; ++mt) {
      const int row = wm * 64 + mt * 16 + fr;
      const int gp = (fg ^ ((row >> 1) & 3)) * 8;
      ah[mt] = *(const bf16x8*)&As_h[buf][row][gp];
      al[mt] = *(const bf16x8*)&As_l[buf][row][gp];
    }
#pragma unroll
    for (int mt = 0; mt < 4; ++mt) {
      acch[mt] = __builtin_amdgcn_mfma_f32_16x16x32_bf16(ah[mt], bhh, acch[mt], 0, 0, 0);
      acch[mt] = __builtin_amdgcn_mfma_f32_16x16x32_bf16(ah[mt], bhl, acch[mt], 0, 0, 0);
      acch[mt] = __builtin_amdgcn_mfma_f32_16x16x32_bf16(al[mt], bhh, acch[mt], 0, 0, 0);
      accz[mt] = __builtin_amdgcn_mfma_f32_16x16x32_bf16(ah[mt], bzh, accz[mt], 0, 0, 0);
      accz[mt] = __builtin_amdgcn_mfma_f32_16x16x32_bf16(ah[mt], bzl, accz[mt], 0, 0, 0);
      accz[mt] = __builtin_amdgcn_mfma_f32_16x16x32_bf16(al[mt], bzh, accz[mt], 0, 0, 0);
    }
  };

  stage(0, 0);
  __syncthreads();
  for (int kk = 0; kk < 16; kk += 2) {
    stage(1, (kk + 1) * 32);
    comp(0);
    __syncthreads();
    if (kk < 14) stage(0, (kk + 2) * 32);
    comp(1);
    __syncthreads();
  }

  const int ecol = lane & 15;
  const int erow = (lane >> 4) * 4;
  const int col = n0 + wn * 16 + ecol;
  const float bh_ = bw[512 + col];
  const float bz_ = bw[1024 + col];
#pragma unroll
  for (int mt = 0; mt < 4; ++mt) {
#pragma unroll
    for (int r = 0; r < 4; ++r) {
      const int row = m0 + wm * 64 + mt * 16 + erow + r;
      const float vh = acch[mt][r] + bh_;
      const float vz = accz[mt][r] + bz_;
      const float hval = (1.f - sigmoidf_(vz)) * tanhf_(vh);
      out[(size_t)(NINT + row) * 512 + col] = hval;
      unsigned short oh, ol;
      split2(hval, oh, ol);
      const size_t ix = (size_t)row * 512 + col;
      hcH[ix] = oh;
      hcL[ix] = ol;
    }
  }
}

// ---------------- child sum (writes split directly) ----------------
__global__ __launch_bounds__(256) void child_sum_k(const float* __restrict__ out,
                                                   int cbase, int nl,
                                                   unsigned short* __restrict__ hH,
                                                   unsigned short* __restrict__ hL) {
  const int idx = blockIdx.x * 256 + threadIdx.x;
  if (idx >= nl * 128) return;
  const int i = idx >> 7;
  const int jq = (idx & 127) << 2;
  const float* b = out + (size_t)(cbase + 4 * i) * 512 + jq;
  const float4 a = *(const float4*)(b);
  const float4 c = *(const float4*)(b + 512);
  const float4 d = *(const float4*)(b + 1024);
  const float4 e = *(const float4*)(b + 1536);
  float4 s;
  s.x = a.x + c.x + d.x + e.x;
  s.y = a.y + c.y + d.y + e.y;
  s.z = a.z + c.z + d.z + e.z;
  s.w = a.w + c.w + d.w + e.w;
  ushort4 sh, sl;
  split2(s.x, sh.x, sl.x); split2(s.y, sh.y, sl.y);
  split2(s.z, sh.z, sl.z); split2(s.w, sh.w, sl.w);
  *(ushort4*)(hH + (size_t)i * 512 + jq) = sh;
  *(ushort4*)(hL + (size_t)i * 512 + jq) = sl;
}

extern "C" void kernel_launch(void* const* d_in, const int* in_sizes, int n_in,
                              void* d_out, int out_size, void* d_ws, size_t ws_size,
                              hipStream_t stream) {
  const float* x   = (const float*)d_in[0];
  const float* Ww  = (const float*)d_in[1];
  const float* bw  = (const float*)d_in[2];
  const float* Ur  = (const float*)d_in[3];
  const float* Uhc = (const float*)d_in[4];
  const float* Uz  = (const float*)d_in[5];
  float* out = (float*)d_out;

  // workspace (~521 MB):
  //   R0 (179 MB): x split during GEMM phase; rh split aliases after x dies.
  //   wx_int 134.2 | hsum split 33.6 | hc split A 134.2 | hc split B 33.6 | W splits 6.3
  char* p = (char*)d_ws;
  unsigned short* x_hi = (unsigned short*)p;
  unsigned short* x_lo = x_hi + (size_t)NNODES * 512;
  unsigned short* rhH = (unsigned short*)p;  // alias R0 (x dead in level loop)
  unsigned short* rhL = rhH + (size_t)16384 * 512;
  p += (size_t)NNODES * 512 * 4;
  float* wx_int = (float*)p;                 p += (size_t)NINT * 1536 * 4;
  unsigned short* hsH = (unsigned short*)p;  p += (size_t)16384 * 512 * 2;
  unsigned short* hsL = (unsigned short*)p;  p += (size_t)16384 * 512 * 2;
  unsigned short* hcH = (unsigned short*)p;  p += (size_t)65536 * 512 * 2;
  unsigned short* hcL = (unsigned short*)p;  p += (size_t)65536 * 512 * 2;
  unsigned short* hc2H = (unsigned short*)p; p += (size_t)16384 * 512 * 2;
  unsigned short* hc2L = (unsigned short*)p; p += (size_t)16384 * 512 * 2;
  unsigned short* W_hi = (unsigned short*)p;   p += (size_t)1536 * 512 * 2;
  unsigned short* W_lo = (unsigned short*)p;   p += (size_t)1536 * 512 * 2;
  unsigned short* Ur_hi = (unsigned short*)p;  p += (size_t)512 * 512 * 2;
  unsigned short* Ur_lo = (unsigned short*)p;  p += (size_t)512 * 512 * 2;
  unsigned short* Uhc_hi = (unsigned short*)p; p += (size_t)512 * 512 * 2;
  unsigned short* Uhc_lo = (unsigned short*)p; p += (size_t)512 * 512 * 2;
  unsigned short* Uz_hi = (unsigned short*)p;  p += (size_t)512 * 512 * 2;
  unsigned short* Uz_lo = (unsigned short*)p;  p += (size_t)512 * 512 * 2;

  // 1. split weights + x
  split_k<<<(1536 * 512 / 4 + 255) / 256, 256, 0, stream>>>(Ww, W_hi, W_lo, 1536 * 512 / 4);
  split_k<<<(512 * 512 / 4 + 255) / 256, 256, 0, stream>>>(Ur, Ur_hi, Ur_lo, 512 * 512 / 4);
  split_k<<<(512 * 512 / 4 + 255) / 256, 256, 0, stream>>>(Uhc, Uhc_hi, Uhc_lo, 512 * 512 / 4);
  split_k<<<(512 * 512 / 4 + 255) / 256, 256, 0, stream>>>(Uz, Uz_hi, Uz_lo, 512 * 512 / 4);
  split_k<<<((int)((size_t)NNODES * 512 / 4) + 255) / 256, 256, 0, stream>>>(
      x, x_hi, x_lo, (int)((size_t)NNODES * 512 / 4));

  // 2. wx for internal nodes (3 gates + bias); grid = 171 m-blocks x 12 n-blocks
  mgemm<3><<<((NINT + 127) / 128) * 12, 512, 0, stream>>>(
      x_hi, x_lo, W_hi, W_lo, wx_int, 1536, NINT, nullptr, 0, bw,
      nullptr, nullptr, nullptr, nullptr, 12);

  // 3. fused leaf h -> out (fp32) + hc split; grid = 512 m-blocks x 8 n-blocks
  mleaf<<<(NLEAF / 128) * 8, 512, 0, stream>>>(
      x_hi + (size_t)NINT * 512, x_lo + (size_t)NINT * 512, W_hi, W_lo, bw, out, hcH, hcL);

  static const int S[10] = {0, 1, 5, 21, 85, 341, 1365, 5461, 21845, 87381};
  unsigned short *rdH = hcH, *rdL = hcL, *wrH = hc2H, *wrL = hc2L;
  for (int l = 1; l <= 8; ++l) {
    const int d = 8 - l;
    const int pbase = S[d];
    const int nl = S[d + 1] - S[d];
    const int cbase = S[d + 1];
    const int el = 4 * nl;

    child_sum_k<<<(nl * 128 + 255) / 256, 256, 0, stream>>>(out, cbase, nl, hsH, hsL);

    const int grm = (nl + 127) / 128;
    // rh = sigmoid(wrx + hsum@Ur^T) * hsum  -> split (rhH, rhL)
    mgemm<1><<<grm * 4, 512, 0, stream>>>(hsH, hsL, Ur_hi, Ur_lo, nullptr, 512, nl,
                                          wx_int, pbase, nullptr, hsH, hsL, rhH, rhL, 4);
    // h_cand = tanh(whx + rh@Uhc^T) -> out[parent rows]
    mgemm<2><<<grm * 4, 512, 0, stream>>>(rhH, rhL, Uhc_hi, Uhc_lo,
                                          out + (size_t)pbase * 512, 512, nl,
                                          wx_int, pbase, nullptr, nullptr, nullptr,
                                          nullptr, nullptr, 4);
    // fused z_e + combine: reads child split (rd), child h (out+cbase),
    // h_cand (out+pbase); writes h (out+pbase) + next-level child split (wr).
    const int gzm = (el + 127) / 128;
    mgemm<4><<<gzm * 4, 512, 0, stream>>>(rdH, rdL, Uz_hi, Uz_lo,
                                          out + (size_t)pbase * 512, 512, el,
                                          wx_int, pbase, out + (size_t)cbase * 512,
                                          nullptr, nullptr, wrH, wrL, 4);
    // ping-pong child-h split buffers (EPI4 writes parents while reading children)
    unsigned short* tH = rdH; rdH = wrH; wrH = tH;
    unsigned short* tL = rdL; rdL = wrL; wrL = tL;
  }
}